// Round 3
// baseline (552.518 us; speedup 1.0000x reference)
//
#include <hip/hip_runtime.h>
#include <hip/hip_bf16.h>
#include <stdint.h>

// QLSTM: T=256, B=2048, DIN=128, NQ=16, 4 gates. fp32 inputs, fp32 outputs.
// Pipeline: (0) input-dtype detector (bf16 vs fp32, device-side, graph-safe)
//           (1) MFMA GEMM projecting x for all timesteps -> xz[T*B,64] (+b+theta folded)
//               fp32 inputs use a hi/lo bf16 split (3 MFMAs) for fp32-grade accuracy
//           (2) recurrent scan, one wave per batch element, lane = (gate,qubit).

#define T_STEPS 256
#define BATCH   2048
#define DIN     128
#define NQ      16
#define LCOLS   64          // 4 gates * 16 qubits
#define DTOT    144         // DIN + NQ
#define ROWS    (T_STEPS * BATCH)   // 524288
#define MTILES  (ROWS / 16)         // 32768

typedef __attribute__((ext_vector_type(8))) short bf16x8;
typedef __attribute__((ext_vector_type(4))) float f32x4;

__device__ __forceinline__ float bf2f(unsigned short u) {
    union { unsigned int i; float f; } v; v.i = ((unsigned int)u) << 16; return v.f;
}
__device__ __forceinline__ unsigned short f2bf(float f) {
    union { float f; unsigned int i; } v; v.f = f;
    unsigned int i = v.i;
    unsigned int r = i + 0x7fffu + ((i >> 16) & 1u);   // round-nearest-even
    return (unsigned short)(r >> 16);
}

__device__ __forceinline__ float ldval(const float* p) { return *p; }
__device__ __forceinline__ float ldval(const unsigned short* p) { return bf2f(*p); }
__device__ __forceinline__ void stval(float* p, float v) { *p = v; }
__device__ __forceinline__ void stval(unsigned short* p, float v) { *p = f2bf(v); }

// ---------------- Kernel 0: dtype detector ----------------
// bf16 data: low 16 bits of each u32 word are a bf16 of ~N(0,1) -> exponent in [100,140].
// fp32 data: those bits are low mantissa bits -> exponent field ~uniform (~16% in range).
__global__ void qlstm_detect(const unsigned int* __restrict__ xw, int* __restrict__ flag) {
    int lane = threadIdx.x;   // 64 threads
    int cnt = 0;
#pragma unroll
    for (int i = 0; i < 4; ++i) {
        unsigned int w = xw[lane + i * 64];
        unsigned int e = (w >> 7) & 0xFFu;
        cnt += (e >= 100u && e <= 140u) ? 1 : 0;
    }
#pragma unroll
    for (int d = 32; d > 0; d >>= 1) cnt += __shfl_down(cnt, d, 64);
    if (lane == 0) *flag = (cnt >= 140) ? 1 : 0;   // bf16 ~256, fp32 ~41
}

// ---------------- Kernel 1: x-projection GEMM (MFMA bf16 16x16x32) ----------------
// xz[row][col] = sum_{d<128} x[row][d] * W[col][d] + b[col] + theta[col]
template <typename OutT>
__global__ __launch_bounds__(256) void qlstm_proj(
    const void* __restrict__ x_, const void* __restrict__ W_,
    const void* __restrict__ b_, const void* __restrict__ th_,
    OutT* __restrict__ xz, const int* __restrict__ flagp)
{
    const int isbf  = __builtin_amdgcn_readfirstlane(*flagp);
    const int lane  = threadIdx.x & 63;
    const int wid   = blockIdx.x * (blockDim.x >> 6) + (threadIdx.x >> 6);
    const int nwv   = gridDim.x * (blockDim.x >> 6);
    const int m     = lane & 15;
    const int quad  = lane >> 4;

    if (isbf) {
        const unsigned short* x  = (const unsigned short*)x_;
        const unsigned short* W  = (const unsigned short*)W_;
        const unsigned short* bv = (const unsigned short*)b_;
        const unsigned short* th = (const unsigned short*)th_;
        bf16x8 bfrag[4][4];
#pragma unroll
        for (int kt = 0; kt < 4; ++kt)
#pragma unroll
            for (int nb = 0; nb < 4; ++nb)
                bfrag[kt][nb] = *(const bf16x8*)(W + (size_t)(nb * 16 + m) * DTOT + kt * 32 + quad * 8);
        float bias[4];
#pragma unroll
        for (int nb = 0; nb < 4; ++nb) {
            int col = nb * 16 + m;
            bias[nb] = bf2f(bv[col]) + bf2f(th[col]);
        }
        for (int mt = wid; mt < MTILES; mt += nwv) {
            const int row0 = mt * 16;
            const unsigned short* xp = x + (size_t)(row0 + m) * DIN + quad * 8;
            bf16x8 a[4];
#pragma unroll
            for (int kt = 0; kt < 4; ++kt) a[kt] = *(const bf16x8*)(xp + kt * 32);
            f32x4 acc[4] = {};
#pragma unroll
            for (int kt = 0; kt < 4; ++kt)
#pragma unroll
                for (int nb = 0; nb < 4; ++nb)
                    acc[nb] = __builtin_amdgcn_mfma_f32_16x16x32_bf16(a[kt], bfrag[kt][nb], acc[nb], 0, 0, 0);
#pragma unroll
            for (int nb = 0; nb < 4; ++nb) {
                int col = nb * 16 + m;
#pragma unroll
                for (int r = 0; r < 4; ++r)
                    stval(xz + (size_t)(row0 + quad * 4 + r) * LCOLS + col, acc[nb][r] + bias[nb]);
            }
        }
    } else {
        const float* x  = (const float*)x_;
        const float* W  = (const float*)W_;
        const float* bv = (const float*)b_;
        const float* th = (const float*)th_;
        // hi/lo split: v = bf16(v) + bf16(v - bf16(v)) + O(2^-18 rel)
        bf16x8 bhi[4][4], blo[4][4];
#pragma unroll
        for (int kt = 0; kt < 4; ++kt)
#pragma unroll
            for (int nb = 0; nb < 4; ++nb) {
                const float* p = W + (size_t)(nb * 16 + m) * DTOT + kt * 32 + quad * 8;
#pragma unroll
                for (int j = 0; j < 8; ++j) {
                    float w = p[j];
                    unsigned short h = f2bf(w);
                    bhi[kt][nb][j] = (short)h;
                    blo[kt][nb][j] = (short)f2bf(w - bf2f(h));
                }
            }
        float bias[4];
#pragma unroll
        for (int nb = 0; nb < 4; ++nb) {
            int col = nb * 16 + m;
            bias[nb] = bv[col] + th[col];
        }
        for (int mt = wid; mt < MTILES; mt += nwv) {
            const int row0 = mt * 16;
            const float* xp = x + (size_t)(row0 + m) * DIN + quad * 8;
            f32x4 xr[8];
#pragma unroll
            for (int kt = 0; kt < 4; ++kt) {
                xr[2 * kt]     = *(const f32x4*)(xp + kt * 32);
                xr[2 * kt + 1] = *(const f32x4*)(xp + kt * 32 + 4);
            }
            f32x4 acc[4] = {};
#pragma unroll
            for (int kt = 0; kt < 4; ++kt) {
                bf16x8 ah, al;
#pragma unroll
                for (int j = 0; j < 8; ++j) {
                    float xv = xr[2 * kt + (j >> 2)][j & 3];
                    unsigned short h = f2bf(xv);
                    ah[j] = (short)h;
                    al[j] = (short)f2bf(xv - bf2f(h));
                }
#pragma unroll
                for (int nb = 0; nb < 4; ++nb)
                    acc[nb] = __builtin_amdgcn_mfma_f32_16x16x32_bf16(ah, bhi[kt][nb], acc[nb], 0, 0, 0);
#pragma unroll
                for (int nb = 0; nb < 4; ++nb)
                    acc[nb] = __builtin_amdgcn_mfma_f32_16x16x32_bf16(al, bhi[kt][nb], acc[nb], 0, 0, 0);
#pragma unroll
                for (int nb = 0; nb < 4; ++nb)
                    acc[nb] = __builtin_amdgcn_mfma_f32_16x16x32_bf16(ah, blo[kt][nb], acc[nb], 0, 0, 0);
            }
#pragma unroll
            for (int nb = 0; nb < 4; ++nb) {
                int col = nb * 16 + m;
#pragma unroll
                for (int r = 0; r < 4; ++r)
                    stval(xz + (size_t)(row0 + quad * 4 + r) * LCOLS + col, acc[nb][r] + bias[nb]);
            }
        }
    }
}

// ---------------- Kernel 2: recurrent scan, one wave per batch element ----------------
template <typename InT>
__global__ __launch_bounds__(256) void qlstm_scan(
    const void* __restrict__ W_,            // [64,144] (cols 128..143 = recurrent part)
    const InT* __restrict__ xz,             // [ROWS,64]
    float* __restrict__ out,                // fp32: outputs [T,B,16] ++ hx [B,16] ++ cx [B,16]
    const int* __restrict__ flagp)
{
    const int isbf = __builtin_amdgcn_readfirstlane(*flagp);
    const int lane = threadIdx.x & 63;
    const int b    = blockIdx.x * (blockDim.x >> 6) + (threadIdx.x >> 6);
    const int g    = lane >> 4;    // gate
    const int n    = lane & 15;    // qubit

    float Wh[16];
    if (isbf) {
        const unsigned short* W = (const unsigned short*)W_;
#pragma unroll
        for (int j = 0; j < 16; ++j) Wh[j] = bf2f(W[(size_t)lane * DTOT + DIN + j]);
    } else {
        const float* W = (const float*)W_;
#pragma unroll
        for (int j = 0; j < 16; ++j) Wh[j] = W[(size_t)lane * DTOT + DIN + j];
    }

    float h = 0.f, c = 0.f, hsave = 0.f;
    float cur = ldval(xz + (size_t)b * LCOLS + lane);
    for (int t = 0; t < T_STEPS; ++t) {
        float nxt = 0.f;
        if (t + 1 < T_STEPS)
            nxt = ldval(xz + ((size_t)((t + 1) * BATCH + b)) * LCOLS + lane);

        // z = xz(+bias folded) + Wh . h   (h replicated per 16-lane segment)
        float z = cur;
#pragma unroll
        for (int j = 0; j < 16; ++j)
            z += Wh[j] * __shfl(h, j, 16);

        float cz = __cosf(z);

        // inclusive prefix product over qubit index within each 16-lane segment
#pragma unroll
        for (int d = 1; d < 16; d <<= 1) {
            float o = __shfl_up(cz, (unsigned)d, 16);
            cz *= (n >= d) ? o : 1.0f;
        }

        // tanh for gate 2, sigmoid otherwise
        float a = (g == 2) ? 2.f * cz : cz;
        float e = __expf(-a);
        float s = (g == 2) ? (1.f - e) / (1.f + e) : 1.f / (1.f + e);

        float fv = __shfl(s, n, 64);
        float iv = __shfl(s, 16 + n, 64);
        float gv = __shfl(s, 32 + n, 64);
        float ov = __shfl(s, 48 + n, 64);

        c = fv * c + iv * gv;
        float e2 = __expf(-2.f * c);          // |c| <= ~3.8, no overflow
        float tc = (1.f - e2) / (1.f + e2);
        h = ov * tc;

        // buffer 4 timesteps; at t%4==3 all 64 lanes store (lane's gate index g picks timestep)
        if ((t & 3) == g) hsave = h;
        if ((t & 3) == 3)
            out[(size_t)(t - 3 + g) * BATCH * NQ + (size_t)b * NQ + n] = hsave;
        cur = nxt;
    }

    if (g == 0) {
        out[(size_t)T_STEPS * BATCH * NQ + (size_t)b * NQ + n] = h;                      // hx
        out[(size_t)T_STEPS * BATCH * NQ + (size_t)BATCH * NQ + (size_t)b * NQ + n] = c; // cx
    }
}

extern "C" void kernel_launch(void* const* d_in, const int* in_sizes, int n_in,
                              void* d_out, int out_size, void* d_ws, size_t ws_size,
                              hipStream_t stream) {
    const void* x  = d_in[0];
    const void* W  = d_in[1];
    const void* bv = d_in[2];
    const void* th = d_in[3];
    float* out = (float*)d_out;

    // flag lives in the last 4 bytes of the workspace
    size_t flag_off = (ws_size >= 8) ? ((ws_size - 4) & ~(size_t)3) : 0;
    int* flagp = (int*)((char*)d_ws + flag_off);
    qlstm_detect<<<1, 64, 0, stream>>>((const unsigned int*)x, flagp);

    const size_t need_f32 = (size_t)ROWS * LCOLS * sizeof(float);  // 128 MiB
    if (ws_size >= need_f32 + 16) {
        float* xz = (float*)d_ws;
        qlstm_proj<float><<<1024, 256, 0, stream>>>(x, W, bv, th, xz, flagp);
        qlstm_scan<float><<<BATCH / 4, 256, 0, stream>>>(W, xz, out, flagp);
    } else {
        unsigned short* xz = (unsigned short*)d_ws;
        qlstm_proj<unsigned short><<<1024, 256, 0, stream>>>(x, W, bv, th, xz, flagp);
        qlstm_scan<unsigned short><<<BATCH / 4, 256, 0, stream>>>(W, xz, out, flagp);
    }
}

// Round 4
// 466.687 us; speedup vs baseline: 1.1839x; 1.1839x over previous
//
#include <hip/hip_runtime.h>
#include <hip/hip_bf16.h>
#include <stdint.h>

// QLSTM: T=256, B=2048, DIN=128, NQ=16, 4 gates. fp32 inputs, fp32 outputs.
// Pipeline: (0) input-dtype detector (bf16 vs fp32, device-side, graph-safe)
//           (1) MFMA GEMM projecting x -> xz[T*B,64] (+b+theta folded), hi/lo bf16 split
//           (2) recurrent scan, one wave per batch element, lane = (gate,qubit).
//               R4: DPP prefix-product, swizzle-broadcast dot, 8-deep prefetch, rcp.

#define T_STEPS 256
#define BATCH   2048
#define DIN     128
#define NQ      16
#define LCOLS   64          // 4 gates * 16 qubits
#define DTOT    144         // DIN + NQ
#define ROWS    (T_STEPS * BATCH)   // 524288
#define MTILES  (ROWS / 16)         // 32768

typedef __attribute__((ext_vector_type(8))) short bf16x8;
typedef __attribute__((ext_vector_type(4))) float f32x4;

__device__ __forceinline__ float bf2f(unsigned short u) {
    union { unsigned int i; float f; } v; v.i = ((unsigned int)u) << 16; return v.f;
}
__device__ __forceinline__ unsigned short f2bf(float f) {
    union { float f; unsigned int i; } v; v.f = f;
    unsigned int i = v.i;
    unsigned int r = i + 0x7fffu + ((i >> 16) & 1u);   // round-nearest-even
    return (unsigned short)(r >> 16);
}

__device__ __forceinline__ float ldval(const float* p) { return *p; }
__device__ __forceinline__ float ldval(const unsigned short* p) { return bf2f(*p); }
__device__ __forceinline__ void stval(float* p, float v) { *p = v; }
__device__ __forceinline__ void stval(unsigned short* p, float v) { *p = f2bf(v); }

// ---------------- Kernel 0: dtype detector ----------------
__global__ void qlstm_detect(const unsigned int* __restrict__ xw, int* __restrict__ flag) {
    int lane = threadIdx.x;   // 64 threads
    int cnt = 0;
#pragma unroll
    for (int i = 0; i < 4; ++i) {
        unsigned int w = xw[lane + i * 64];
        unsigned int e = (w >> 7) & 0xFFu;
        cnt += (e >= 100u && e <= 140u) ? 1 : 0;
    }
#pragma unroll
    for (int d = 32; d > 0; d >>= 1) cnt += __shfl_down(cnt, d, 64);
    if (lane == 0) *flag = (cnt >= 140) ? 1 : 0;   // bf16 ~256, fp32 ~41
}

// ---------------- Kernel 1: x-projection GEMM (MFMA bf16 16x16x32) ----------------
template <typename OutT>
__global__ __launch_bounds__(256) void qlstm_proj(
    const void* __restrict__ x_, const void* __restrict__ W_,
    const void* __restrict__ b_, const void* __restrict__ th_,
    OutT* __restrict__ xz, const int* __restrict__ flagp)
{
    const int isbf  = __builtin_amdgcn_readfirstlane(*flagp);
    const int lane  = threadIdx.x & 63;
    const int wid   = blockIdx.x * (blockDim.x >> 6) + (threadIdx.x >> 6);
    const int nwv   = gridDim.x * (blockDim.x >> 6);
    const int m     = lane & 15;
    const int quad  = lane >> 4;

    if (isbf) {
        const unsigned short* x  = (const unsigned short*)x_;
        const unsigned short* W  = (const unsigned short*)W_;
        const unsigned short* bv = (const unsigned short*)b_;
        const unsigned short* th = (const unsigned short*)th_;
        bf16x8 bfrag[4][4];
#pragma unroll
        for (int kt = 0; kt < 4; ++kt)
#pragma unroll
            for (int nb = 0; nb < 4; ++nb)
                bfrag[kt][nb] = *(const bf16x8*)(W + (size_t)(nb * 16 + m) * DTOT + kt * 32 + quad * 8);
        float bias[4];
#pragma unroll
        for (int nb = 0; nb < 4; ++nb) {
            int col = nb * 16 + m;
            bias[nb] = bf2f(bv[col]) + bf2f(th[col]);
        }
        for (int mt = wid; mt < MTILES; mt += nwv) {
            const int row0 = mt * 16;
            const unsigned short* xp = x + (size_t)(row0 + m) * DIN + quad * 8;
            bf16x8 a[4];
#pragma unroll
            for (int kt = 0; kt < 4; ++kt) a[kt] = *(const bf16x8*)(xp + kt * 32);
            f32x4 acc[4] = {};
#pragma unroll
            for (int kt = 0; kt < 4; ++kt)
#pragma unroll
                for (int nb = 0; nb < 4; ++nb)
                    acc[nb] = __builtin_amdgcn_mfma_f32_16x16x32_bf16(a[kt], bfrag[kt][nb], acc[nb], 0, 0, 0);
#pragma unroll
            for (int nb = 0; nb < 4; ++nb) {
                int col = nb * 16 + m;
#pragma unroll
                for (int r = 0; r < 4; ++r)
                    stval(xz + (size_t)(row0 + quad * 4 + r) * LCOLS + col, acc[nb][r] + bias[nb]);
            }
        }
    } else {
        const float* x  = (const float*)x_;
        const float* W  = (const float*)W_;
        const float* bv = (const float*)b_;
        const float* th = (const float*)th_;
        bf16x8 bhi[4][4], blo[4][4];
#pragma unroll
        for (int kt = 0; kt < 4; ++kt)
#pragma unroll
            for (int nb = 0; nb < 4; ++nb) {
                const float* p = W + (size_t)(nb * 16 + m) * DTOT + kt * 32 + quad * 8;
#pragma unroll
                for (int j = 0; j < 8; ++j) {
                    float w = p[j];
                    unsigned short h = f2bf(w);
                    bhi[kt][nb][j] = (short)h;
                    blo[kt][nb][j] = (short)f2bf(w - bf2f(h));
                }
            }
        float bias[4];
#pragma unroll
        for (int nb = 0; nb < 4; ++nb) {
            int col = nb * 16 + m;
            bias[nb] = bv[col] + th[col];
        }
        for (int mt = wid; mt < MTILES; mt += nwv) {
            const int row0 = mt * 16;
            const float* xp = x + (size_t)(row0 + m) * DIN + quad * 8;
            f32x4 xr[8];
#pragma unroll
            for (int kt = 0; kt < 4; ++kt) {
                xr[2 * kt]     = *(const f32x4*)(xp + kt * 32);
                xr[2 * kt + 1] = *(const f32x4*)(xp + kt * 32 + 4);
            }
            f32x4 acc[4] = {};
#pragma unroll
            for (int kt = 0; kt < 4; ++kt) {
                bf16x8 ah, al;
#pragma unroll
                for (int j = 0; j < 8; ++j) {
                    float xv = xr[2 * kt + (j >> 2)][j & 3];
                    unsigned short h = f2bf(xv);
                    ah[j] = (short)h;
                    al[j] = (short)f2bf(xv - bf2f(h));
                }
#pragma unroll
                for (int nb = 0; nb < 4; ++nb)
                    acc[nb] = __builtin_amdgcn_mfma_f32_16x16x32_bf16(ah, bhi[kt][nb], acc[nb], 0, 0, 0);
#pragma unroll
                for (int nb = 0; nb < 4; ++nb)
                    acc[nb] = __builtin_amdgcn_mfma_f32_16x16x32_bf16(al, bhi[kt][nb], acc[nb], 0, 0, 0);
#pragma unroll
                for (int nb = 0; nb < 4; ++nb)
                    acc[nb] = __builtin_amdgcn_mfma_f32_16x16x32_bf16(ah, blo[kt][nb], acc[nb], 0, 0, 0);
            }
#pragma unroll
            for (int nb = 0; nb < 4; ++nb) {
                int col = nb * 16 + m;
#pragma unroll
                for (int r = 0; r < 4; ++r)
                    stval(xz + (size_t)(row0 + quad * 4 + r) * LCOLS + col, acc[nb][r] + bias[nb]);
            }
        }
    }
}

// ---------------- Kernel 2: recurrent scan ----------------
// DPP shift-by-CTRL with multiplicative identity fill (width-16 shfl_up equivalent)
template <int CTRL>
__device__ __forceinline__ float dpp_sh(float v) {
    int r = __builtin_amdgcn_update_dpp(__builtin_bit_cast(int, 1.0f),
                                        __builtin_bit_cast(int, v),
                                        CTRL, 0xF, 0xF, false);
    return __builtin_bit_cast(float, r);
}
// ds_swizzle broadcast of local lane J (within each 32-lane half); h is replicated
// across gates so both halves hold h_J at local lane J.
template <int J>
__device__ __forceinline__ float bcast16(float v) {
    int r = __builtin_amdgcn_ds_swizzle(__builtin_bit_cast(int, v), (J << 5));
    return __builtin_bit_cast(float, r);
}

template <int BASE>
__device__ __forceinline__ void qstep(int t, int g, int n, float cur,
                                      const float (&Wh)[16], float& h, float& c,
                                      float& hsave, float* __restrict__ out, int b)
{
    float hb0  = bcast16<0>(h),  hb1  = bcast16<1>(h),  hb2  = bcast16<2>(h),  hb3  = bcast16<3>(h);
    float hb4  = bcast16<4>(h),  hb5  = bcast16<5>(h),  hb6  = bcast16<6>(h),  hb7  = bcast16<7>(h);
    float hb8  = bcast16<8>(h),  hb9  = bcast16<9>(h),  hb10 = bcast16<10>(h), hb11 = bcast16<11>(h);
    float hb12 = bcast16<12>(h), hb13 = bcast16<13>(h), hb14 = bcast16<14>(h), hb15 = bcast16<15>(h);

    float s0 = fmaf(Wh[0],  hb0,  fmaf(Wh[1],  hb1,  fmaf(Wh[2],  hb2,  Wh[3]  * hb3)));
    float s1 = fmaf(Wh[4],  hb4,  fmaf(Wh[5],  hb5,  fmaf(Wh[6],  hb6,  Wh[7]  * hb7)));
    float s2 = fmaf(Wh[8],  hb8,  fmaf(Wh[9],  hb9,  fmaf(Wh[10], hb10, Wh[11] * hb11)));
    float s3 = fmaf(Wh[12], hb12, fmaf(Wh[13], hb13, fmaf(Wh[14], hb14, Wh[15] * hb15)));
    float z = cur + ((s0 + s1) + (s2 + s3));

    float cz = __cosf(z);
    // inclusive prefix product over the 16-lane row (DPP Hillis-Steele)
    cz *= dpp_sh<BASE + 1>(cz);
    cz *= dpp_sh<BASE + 2>(cz);
    cz *= dpp_sh<BASE + 4>(cz);
    cz *= dpp_sh<BASE + 8>(cz);

    float a = (g == 2) ? 2.f * cz : cz;
    float e = __expf(-a);
    float rr = __builtin_amdgcn_rcpf(1.f + e);
    float s = (g == 2) ? (1.f - e) * rr : rr;

    float fv = __shfl(s, n, 64);
    float iv = __shfl(s, 16 + n, 64);
    float gv = __shfl(s, 32 + n, 64);
    float ov = __shfl(s, 48 + n, 64);

    c = fmaf(fv, c, iv * gv);
    float e2 = __expf(-2.f * c);
    float tc = (1.f - e2) * __builtin_amdgcn_rcpf(1.f + e2);
    h = ov * tc;

    if ((t & 3) == g) hsave = h;
    if ((t & 3) == 3)
        out[(size_t)(t - 3 + g) * (BATCH * NQ) + (size_t)b * NQ + n] = hsave;
}

template <int BASE, typename InT>
__device__ __forceinline__ void scan_main(const InT* __restrict__ xz,
                                          float* __restrict__ out,
                                          int b, int lane, const float (&Wh)[16])
{
    const int g = lane >> 4, n = lane & 15;
    float h = 0.f, c = 0.f, hsave = 0.f;
    const InT* xp = xz + (size_t)b * LCOLS + lane;
    const size_t ts = (size_t)BATCH * LCOLS;    // stride between timesteps

    float A[8], Bb[8];
#pragma unroll
    for (int j = 0; j < 8; ++j) A[j] = ldval(xp + (size_t)j * ts);

    for (int ch = 0; ch < 32; ch += 2) {
        const InT* pn = xp + (size_t)(ch + 1) * 8 * ts;
#pragma unroll
        for (int j = 0; j < 8; ++j) Bb[j] = ldval(pn + (size_t)j * ts);
#pragma unroll
        for (int j = 0; j < 8; ++j) qstep<BASE>(ch * 8 + j, g, n, A[j], Wh, h, c, hsave, out, b);
        if (ch + 2 < 32) {
            const InT* pa = xp + (size_t)(ch + 2) * 8 * ts;
#pragma unroll
            for (int j = 0; j < 8; ++j) A[j] = ldval(pa + (size_t)j * ts);
        }
#pragma unroll
        for (int j = 0; j < 8; ++j) qstep<BASE>((ch + 1) * 8 + j, g, n, Bb[j], Wh, h, c, hsave, out, b);
    }

    if (g == 0) {
        out[(size_t)T_STEPS * BATCH * NQ + (size_t)b * NQ + n] = h;                       // hx
        out[(size_t)T_STEPS * BATCH * NQ + (size_t)BATCH * NQ + (size_t)b * NQ + n] = c;  // cx
    }
}

template <typename InT>
__global__ __launch_bounds__(256) void qlstm_scan(
    const void* __restrict__ W_, const InT* __restrict__ xz,
    float* __restrict__ out, const int* __restrict__ flagp)
{
    const int isbf = __builtin_amdgcn_readfirstlane(*flagp);
    const int lane = threadIdx.x & 63;
    const int b    = blockIdx.x * (blockDim.x >> 6) + (threadIdx.x >> 6);

    float Wh[16];
    if (isbf) {
        const unsigned short* W = (const unsigned short*)W_;
#pragma unroll
        for (int j = 0; j < 16; ++j) Wh[j] = bf2f(W[(size_t)lane * DTOT + DIN + j]);
    } else {
        const float* W = (const float*)W_;
#pragma unroll
        for (int j = 0; j < 16; ++j) Wh[j] = W[(size_t)lane * DTOT + DIN + j];
    }

    // runtime probe of DPP row_shr direction (wave-uniform)
    int probe = __builtin_amdgcn_update_dpp(999, lane, 0x111, 0xF, 0xF, false);
    int p2 = __shfl(probe, 2, 64);
    if (p2 == 1) scan_main<0x110>(xz, out, b, lane, Wh);   // row_shr = from lane-i-N (expected)
    else         scan_main<0x100>(xz, out, b, lane, Wh);   // flipped semantics -> row_shl
}

extern "C" void kernel_launch(void* const* d_in, const int* in_sizes, int n_in,
                              void* d_out, int out_size, void* d_ws, size_t ws_size,
                              hipStream_t stream) {
    const void* x  = d_in[0];
    const void* W  = d_in[1];
    const void* bv = d_in[2];
    const void* th = d_in[3];
    float* out = (float*)d_out;

    size_t flag_off = (ws_size >= 8) ? ((ws_size - 4) & ~(size_t)3) : 0;
    int* flagp = (int*)((char*)d_ws + flag_off);
    qlstm_detect<<<1, 64, 0, stream>>>((const unsigned int*)x, flagp);

    const size_t need_f32 = (size_t)ROWS * LCOLS * sizeof(float);  // 128 MiB
    if (ws_size >= need_f32 + 16) {
        float* xz = (float*)d_ws;
        qlstm_proj<float><<<1024, 256, 0, stream>>>(x, W, bv, th, xz, flagp);
        qlstm_scan<float><<<BATCH / 4, 256, 0, stream>>>(W, xz, out, flagp);
    } else {
        unsigned short* xz = (unsigned short*)d_ws;
        qlstm_proj<unsigned short><<<1024, 256, 0, stream>>>(x, W, bv, th, xz, flagp);
        qlstm_scan<unsigned short><<<BATCH / 4, 256, 0, stream>>>(W, xz, out, flagp);
    }
}